// Round 1
// baseline (594.191 us; speedup 1.0000x reference)
//
#include <hip/hip_runtime.h>
#include <math.h>

// MaskedConvFlow fused fp32 kernel.
// x:  [32][64][64][64]  (B, C_IN, H, W)
// Wm: [256][64][2][3]   -> flat [co][k], k = ci*6 + kh*3 + kw  (384)
// bm: [256]
// W1: [128][256]
// b1: [128]
// out: [32][64][64][64] floats, then logdet [32]
//
// One block per (b,h). Phase1: c[256][64] = relu(Wm * patches + bm).
// Phase2: p[128][64] = W1 * c + b1. Epilogue: scale=sigmoid(ls+2),
// out = scale*x + mu, per-row logdet partial -> ws; kernel2 reduces.

#define B_DIM 32
#define H_DIM 64
#define W_DIM 64
#define CIN 64
#define CHID 256
#define COUT 128

__global__ __launch_bounds__(256) void mcf_fused(
    const float* __restrict__ x, const float* __restrict__ Wm,
    const float* __restrict__ bm, const float* __restrict__ W1,
    const float* __restrict__ b1, float* __restrict__ out,
    float* __restrict__ row_ld)
{
    // LDS: xs 8448 f + cs 256*68 f + ps 128*68 f + red 256 f = 34816 f = 139264 B
    __shared__ float xs[2 * 64 * 66];
    __shared__ float cs[256 * 68];
    __shared__ float ps[128 * 68];
    __shared__ float red[256];

    const int blk = blockIdx.x;
    const int b = blk >> 6;
    const int h = blk & 63;
    const int tid = threadIdx.x;

    // ---- stage input rows h-2, h-1 (zero padded) ----
    // xs[kh][ci][wc] = x[b][ci][h-2+kh][wc-1], wc in [0,66)
    for (int l = tid; l < 2 * 64 * 66; l += 256) {
        int wc = l % 66;
        int rest = l / 66;
        int ci = rest & 63;
        int kh = rest >> 6;
        int r = h - 2 + kh;
        float v = 0.f;
        if (r >= 0 && wc >= 1 && wc <= 64) {
            v = x[(((size_t)b * CIN + ci) * H_DIM + r) * W_DIM + (wc - 1)];
        }
        xs[l] = v;
    }
    __syncthreads();

    // ---- phase 1: c = relu(conv + bm) ----
    {
        const int tn = tid & 7;          // w group (8 cols)
        const int tm = tid >> 3;         // co group (8 rows)
        const int w0 = tn * 8;
        const int co0 = tm * 8;
        float acc[8][8];
        #pragma unroll
        for (int i = 0; i < 8; ++i) {
            float bv = bm[co0 + i];
            #pragma unroll
            for (int j = 0; j < 8; ++j) acc[i][j] = bv;
        }
        for (int ci = 0; ci < CIN; ++ci) {
            #pragma unroll
            for (int kh = 0; kh < 2; ++kh) {
                float xv[10];
                const float* xrow = &xs[(kh * 64 + ci) * 66 + w0];
                #pragma unroll
                for (int t = 0; t < 10; ++t) xv[t] = xrow[t];
                const float* wrow = Wm + (size_t)co0 * 384 + ci * 6 + kh * 3;
                #pragma unroll
                for (int i = 0; i < 8; ++i) {
                    float a0 = wrow[i * 384 + 0];
                    float a1 = wrow[i * 384 + 1];
                    float a2 = wrow[i * 384 + 2];
                    #pragma unroll
                    for (int j = 0; j < 8; ++j) {
                        acc[i][j] = fmaf(a0, xv[j],     acc[i][j]);
                        acc[i][j] = fmaf(a1, xv[j + 1], acc[i][j]);
                        acc[i][j] = fmaf(a2, xv[j + 2], acc[i][j]);
                    }
                }
            }
        }
        #pragma unroll
        for (int i = 0; i < 8; ++i) {
            #pragma unroll
            for (int j = 0; j < 8; ++j) {
                cs[(co0 + i) * 68 + w0 + j] = fmaxf(acc[i][j], 0.f);
            }
        }
    }
    __syncthreads();

    // ---- phase 2: p = W1 * c + b1 ----
    {
        const int tn = tid & 15;         // w group (4 cols)
        const int tm = tid >> 4;         // o group (8 rows)
        const int w0 = tn * 4;
        const int o0 = tm * 8;
        float pacc[8][4];
        #pragma unroll
        for (int i = 0; i < 8; ++i) {
            float bv = b1[o0 + i];
            #pragma unroll
            for (int j = 0; j < 4; ++j) pacc[i][j] = bv;
        }
        for (int k = 0; k < CHID; k += 4) {
            float cv[4][4];
            #pragma unroll
            for (int t = 0; t < 4; ++t) {
                float4 c4 = *reinterpret_cast<const float4*>(&cs[(k + t) * 68 + w0]);
                cv[t][0] = c4.x; cv[t][1] = c4.y; cv[t][2] = c4.z; cv[t][3] = c4.w;
            }
            #pragma unroll
            for (int i = 0; i < 8; ++i) {
                float4 w4 = *reinterpret_cast<const float4*>(&W1[(size_t)(o0 + i) * CHID + k]);
                float wk[4] = {w4.x, w4.y, w4.z, w4.w};
                #pragma unroll
                for (int t = 0; t < 4; ++t) {
                    #pragma unroll
                    for (int j = 0; j < 4; ++j) {
                        pacc[i][j] = fmaf(wk[t], cv[t][j], pacc[i][j]);
                    }
                }
            }
        }
        #pragma unroll
        for (int i = 0; i < 8; ++i) {
            float4 p4;
            p4.x = pacc[i][0]; p4.y = pacc[i][1]; p4.z = pacc[i][2]; p4.w = pacc[i][3];
            *reinterpret_cast<float4*>(&ps[(o0 + i) * 68 + w0]) = p4;
        }
    }
    __syncthreads();

    // ---- epilogue: scale = sigmoid(ls+2); out = scale*x + mu; logdet ----
    float ld = 0.f;
    for (int idx = tid; idx < CIN * W_DIM; idx += 256) {
        int co = idx >> 6;
        int w = idx & 63;
        float mu = ps[co * 68 + w];
        float lsv = ps[(co + 64) * 68 + w];
        float scale = 1.f / (1.f + expf(-(lsv + 2.f)));
        size_t xi = (((size_t)b * CIN + co) * H_DIM + h) * W_DIM + w;
        out[xi] = scale * x[xi] + mu;
        ld += logf(scale);
    }

    red[tid] = ld;
    __syncthreads();
    if (tid < 128) red[tid] += red[tid + 128];
    __syncthreads();
    if (tid < 64) {
        float v = red[tid] + red[tid + 64];
        #pragma unroll
        for (int off = 32; off; off >>= 1) v += __shfl_down(v, off);
        if (tid == 0) row_ld[blk] = v;
    }
}

__global__ __launch_bounds__(64) void mcf_ldreduce(
    const float* __restrict__ row_ld, float* __restrict__ ldout)
{
    int b = blockIdx.x;
    float v = row_ld[b * 64 + threadIdx.x];
    #pragma unroll
    for (int off = 32; off; off >>= 1) v += __shfl_down(v, off);
    if (threadIdx.x == 0) ldout[b] = v;
}

extern "C" void kernel_launch(void* const* d_in, const int* in_sizes, int n_in,
                              void* d_out, int out_size, void* d_ws, size_t ws_size,
                              hipStream_t stream) {
    const float* x  = (const float*)d_in[0];
    const float* Wm = (const float*)d_in[1];
    const float* bm = (const float*)d_in[2];
    const float* W1 = (const float*)d_in[3];
    const float* b1 = (const float*)d_in[4];
    float* out = (float*)d_out;
    float* row_ld = (float*)d_ws;   // 2048 floats

    hipLaunchKernelGGL(mcf_fused, dim3(B_DIM * H_DIM), dim3(256), 0, stream,
                       x, Wm, bm, W1, b1, out, row_ld);
    hipLaunchKernelGGL(mcf_ldreduce, dim3(B_DIM), dim3(64), 0, stream,
                       row_ld, out + (size_t)B_DIM * CIN * H_DIM * W_DIM);
}

// Round 2
// 117.971 us; speedup vs baseline: 5.0367x; 5.0367x over previous
//
#include <hip/hip_runtime.h>
#include <math.h>

// MaskedConvFlow — bf16 MFMA fused kernel.
// x:  [32][64][64][64] f32 (B, C_IN, H, W)
// Wm: [256][64][2][3]  f32 -> prep -> Wm_r bf16 [kw][co][k2], k2 = ci*2+kh
// W1: [128][256]       f32 -> prep -> W1_bf bf16 [o][k]
// One block per (b,h), 512 threads (8 waves).
//   Stage Xt[r][k2] bf16 (r = w+1, rows 0/65 zero pad).
//   GEMM1: c[256][64] = relu(sum_kw Wm_r[kw] @ Xt(shifted by kw) + bm) -> Ct bf16.
//   GEMM2: p[128][64] = W1_bf @ Ct + b1; epilogue in-register:
//   scale = sigmoid(ls+2), out = scale*x + mu, logdet partial -> ws.

#define BATCH 32
#define HDIM 64
#define WDIM 64
#define CIN 64
#define CHID 256
#define COUT 128

#define XT_LD 136   // 128 + 8 pad (16B-aligned rows, 2-way banks only)
#define CT_LD 264   // 256 + 8 pad

typedef __attribute__((ext_vector_type(8))) short short8;
typedef __attribute__((ext_vector_type(4))) float f32x4;

__device__ inline unsigned short f2bf(float f) {
    union { float f; unsigned int u; } v; v.f = f;
    unsigned int u = v.u;
    unsigned int r = u + 0x7FFFu + ((u >> 16) & 1u);   // RNE
    return (unsigned short)(r >> 16);
}

// ---- prep: weight convert/repack to bf16 ----
__global__ __launch_bounds__(256) void mcf_prep(
    const float* __restrict__ Wm, const float* __restrict__ W1,
    unsigned short* __restrict__ Wm_r, unsigned short* __restrict__ W1_bf)
{
    int idx = blockIdx.x * 256 + threadIdx.x;
    if (idx < 3 * 256 * 128) {
        int kw = idx >> 15;
        int rem = idx & 32767;
        int co = rem >> 7;
        int k2 = rem & 127;
        int ci = k2 >> 1;
        int kh = k2 & 1;
        Wm_r[idx] = f2bf(Wm[((co * 64 + ci) * 2 + kh) * 3 + kw]);
    } else {
        int i = idx - 3 * 256 * 128;
        if (i < 128 * 256) W1_bf[i] = f2bf(W1[i]);
    }
}

__global__ __launch_bounds__(512, 4) void mcf_mfma(
    const float* __restrict__ x,
    const unsigned short* __restrict__ Wm_r,
    const float* __restrict__ bm,
    const unsigned short* __restrict__ W1_bf,
    const float* __restrict__ b1,
    float* __restrict__ out, float* __restrict__ row_ld)
{
    __shared__ unsigned short Xt[66 * XT_LD];   // 17952 B
    __shared__ unsigned short Ct[64 * CT_LD];   // 33792 B
    __shared__ float red[8];

    const int blk = blockIdx.x;
    const int b = blk >> 6;
    const int h = blk & 63;
    const int tid = threadIdx.x;
    const int lane = tid & 63;
    const int wv = tid >> 6;
    const int col = lane & 15;
    const int g = lane >> 4;

    // ---- stage Xt[w'+1][ci*2+kh] = bf16(x[b][ci][h-2+kh][w']) ----
    if (tid < 2 * XT_LD) {   // zero pad rows 0 and 65
        int r = (tid < XT_LD) ? 0 : 65;
        int c = (tid < XT_LD) ? tid : tid - XT_LD;
        Xt[r * XT_LD + c] = 0;
    }
    #pragma unroll
    for (int it = 0; it < 16; ++it) {
        int idx = it * 512 + tid;       // 8192 = 64 w * 128 k2
        int wq = idx & 63;
        int pair = idx >> 6;            // ci*2+kh
        int kh = pair & 1;
        int ci = pair >> 1;
        int r = h - 2 + kh;
        float v = 0.f;
        if (r >= 0) v = x[(((size_t)b * CIN + ci) * HDIM + r) * WDIM + wq];
        Xt[(wq + 1) * XT_LD + pair] = f2bf(v);
    }
    __syncthreads();

    // ---- GEMM1: wave wv -> co-tiles {2wv, 2wv+1} x w-tiles 0..3 ----
    {
        f32x4 acc[2][4];
        #pragma unroll
        for (int ct = 0; ct < 2; ++ct) {
            int co_base = wv * 32 + ct * 16 + g * 4;
            #pragma unroll
            for (int j = 0; j < 4; ++j) {
                float bv = bm[co_base + j];
                #pragma unroll
                for (int wt = 0; wt < 4; ++wt) acc[ct][wt][j] = bv;
            }
        }
        #pragma unroll
        for (int kw = 0; kw < 3; ++kw) {
            const unsigned short* wmk = Wm_r + kw * (256 * 128);
            #pragma unroll
            for (int ks = 0; ks < 4; ++ks) {
                int kk = ks * 32 + g * 8;
                short8 bfrag[4];
                #pragma unroll
                for (int wt = 0; wt < 4; ++wt) {
                    int row = wt * 16 + col + kw;    // = w + kw, row w+1-1+kw
                    bfrag[wt] = *reinterpret_cast<const short8*>(&Xt[row * XT_LD + kk]);
                }
                #pragma unroll
                for (int ct = 0; ct < 2; ++ct) {
                    int co = wv * 32 + ct * 16 + col;
                    short8 afrag = *reinterpret_cast<const short8*>(&wmk[co * 128 + kk]);
                    #pragma unroll
                    for (int wt = 0; wt < 4; ++wt) {
                        acc[ct][wt] = __builtin_amdgcn_mfma_f32_16x16x32_bf16(
                            afrag, bfrag[wt], acc[ct][wt], 0, 0, 0);
                    }
                }
            }
        }
        // relu -> bf16 -> Ct[w][co] (lane holds 4 consecutive co rows)
        #pragma unroll
        for (int ct = 0; ct < 2; ++ct) {
            int co_base = wv * 32 + ct * 16 + g * 4;
            #pragma unroll
            for (int wt = 0; wt < 4; ++wt) {
                int w = wt * 16 + col;
                unsigned short pk[4];
                #pragma unroll
                for (int j = 0; j < 4; ++j) pk[j] = f2bf(fmaxf(acc[ct][wt][j], 0.f));
                *reinterpret_cast<unsigned long long*>(&Ct[w * CT_LD + co_base]) =
                    *reinterpret_cast<const unsigned long long*>(pk);
            }
        }
    }
    __syncthreads();

    // ---- GEMM2 + fused epilogue ----
    {
        const int pr = wv & 3;      // mu row-tile; ls row-tile = pr+4
        const int wcg = wv >> 2;    // w-tiles {2wcg, 2wcg+1}
        f32x4 accM[2], accL[2];
        int omu = pr * 16 + g * 4;
        #pragma unroll
        for (int j = 0; j < 4; ++j) {
            float bmu = b1[omu + j];
            float bls = b1[omu + 64 + j];
            accM[0][j] = bmu; accM[1][j] = bmu;
            accL[0][j] = bls; accL[1][j] = bls;
        }
        #pragma unroll
        for (int ks = 0; ks < 8; ++ks) {
            int kk = ks * 32 + g * 8;
            short8 bfrag[2];
            #pragma unroll
            for (int wt = 0; wt < 2; ++wt) {
                int w = (wcg * 2 + wt) * 16 + col;
                bfrag[wt] = *reinterpret_cast<const short8*>(&Ct[w * CT_LD + kk]);
            }
            int oA = pr * 16 + col;
            short8 aM = *reinterpret_cast<const short8*>(&W1_bf[oA * 256 + kk]);
            short8 aL = *reinterpret_cast<const short8*>(&W1_bf[(oA + 64) * 256 + kk]);
            #pragma unroll
            for (int wt = 0; wt < 2; ++wt) {
                accM[wt] = __builtin_amdgcn_mfma_f32_16x16x32_bf16(aM, bfrag[wt], accM[wt], 0, 0, 0);
                accL[wt] = __builtin_amdgcn_mfma_f32_16x16x32_bf16(aL, bfrag[wt], accL[wt], 0, 0, 0);
            }
        }
        float ld = 0.f;
        #pragma unroll
        for (int wt = 0; wt < 2; ++wt) {
            int w = (wcg * 2 + wt) * 16 + col;
            #pragma unroll
            for (int j = 0; j < 4; ++j) {
                int co = pr * 16 + g * 4 + j;
                float mu = accM[wt][j];
                float ls = accL[wt][j];
                float scale = 1.f / (1.f + __expf(-(ls + 2.f)));
                size_t xi = (((size_t)b * CIN + co) * HDIM + h) * WDIM + w;
                out[xi] = scale * x[xi] + mu;
                ld += __logf(scale);
            }
        }
        #pragma unroll
        for (int off = 32; off; off >>= 1) ld += __shfl_down(ld, off);
        if (lane == 0) red[wv] = ld;
    }
    __syncthreads();
    if (tid == 0) {
        float s = 0.f;
        #pragma unroll
        for (int i = 0; i < 8; ++i) s += red[i];
        row_ld[blk] = s;
    }
}

__global__ __launch_bounds__(64) void mcf_ldreduce(
    const float* __restrict__ row_ld, float* __restrict__ ldout)
{
    int b = blockIdx.x;
    float v = row_ld[b * 64 + threadIdx.x];
    #pragma unroll
    for (int off = 32; off; off >>= 1) v += __shfl_down(v, off);
    if (threadIdx.x == 0) ldout[b] = v;
}

extern "C" void kernel_launch(void* const* d_in, const int* in_sizes, int n_in,
                              void* d_out, int out_size, void* d_ws, size_t ws_size,
                              hipStream_t stream) {
    const float* x  = (const float*)d_in[0];
    const float* Wm = (const float*)d_in[1];
    const float* bm = (const float*)d_in[2];
    const float* W1 = (const float*)d_in[3];
    const float* b1 = (const float*)d_in[4];
    float* out = (float*)d_out;

    float* row_ld = (float*)d_ws;                                   // 8192 B
    unsigned short* Wm_r  = (unsigned short*)((char*)d_ws + 8192);  // 196608 B
    unsigned short* W1_bf = Wm_r + 3 * 256 * 128;                   // 65536 B

    hipLaunchKernelGGL(mcf_prep, dim3(512), dim3(256), 0, stream,
                       Wm, W1, Wm_r, W1_bf);
    hipLaunchKernelGGL(mcf_mfma, dim3(BATCH * HDIM), dim3(512), 0, stream,
                       x, Wm_r, bm, W1_bf, b1, out, row_ld);
    hipLaunchKernelGGL(mcf_ldreduce, dim3(BATCH), dim3(64), 0, stream,
                       row_ld, out + (size_t)BATCH * CIN * HDIM * WDIM);
}